// Round 21
// baseline (344.747 us; speedup 1.0000x reference)
//
#include <hip/hip_runtime.h>

#define NA 15
#define GH 34
#define GW 34
#define SP (GH*GW)          // 1156
#define NB (SP*NA)          // 17340
#define MAXC 5000
#define TOPN 300
#define NW 80               // padded words per mask row (79 used + 1 pad)
#define NRALLOC 5056        // mask rows allocated
#define THRESH_OBJ 0.2f
#define NMS_T 0.7f
// score-bucket constants: positive-float bits are order-preserving
#define SH 12
#define BLO 0x3E4CCu        // bits(0.2f) >> 12
#define NBUCK 5120          // covers bits(1.0)>>12 - BLO = 4916, 5 per scan-thread

typedef unsigned long long u64;
typedef unsigned int u32;
struct __align__(16) U2 { u64 x, y; };

__constant__ float c_aw[NA] = {45.3f,32.0f,22.6f,90.5f,64.0f,45.3f,181.0f,128.0f,90.5f,271.5f,192.0f,135.8f,362.0f,256.0f,181.0f};
__constant__ float c_ah[NA] = {22.6f,32.0f,45.3f,45.3f,64.0f,90.5f,90.5f,128.0f,181.0f,135.8f,192.0f,271.5f,181.0f,256.0f,362.0f};

// ---------------- decode: anchors + deltas -> proposals + score bits ----------------
__global__ __launch_bounds__(256) void k_decode(
    const float* __restrict__ cls, const float* __restrict__ pred,
    const int* __restrict__ iminfo, const float* __restrict__ mean,
    const float* __restrict__ stdv, float* __restrict__ boxes,
    u32* __restrict__ sbits) {
#pragma clang fp contract(off)
  int r = blockIdx.x * 256 + threadIdx.x;
  if (r >= NB) return;
  int n = r % NA;
  int p = r / NA;       // p = h*GW + w
  int w = p % GW;
  int h = p / GW;

  float score = cls[(NA + n) * SP + p];             // channel NA+n, spatial p

  float d0 = pred[(n*4+0)*SP + p] * stdv[0] + mean[0];
  float d1 = pred[(n*4+1)*SP + p] * stdv[1] + mean[1];
  float d2 = pred[(n*4+2)*SP + p] * stdv[2] + mean[2];
  float d3 = pred[(n*4+3)*SP + p] * stdv[3] + mean[3];

  float aw = c_aw[n], ah = c_ah[n];
  float sx = (float)(w * 16);
  float sy = (float)(h * 16);
  float xmin = -0.5f * (aw - 1.0f) + sx;
  float ymin = -0.5f * (ah - 1.0f) + sy;
  float xmax =  0.5f * (aw - 1.0f) + sx;
  float ymax =  0.5f * (ah - 1.0f) + sy;

  float widths  = xmax - xmin + 1.0f;
  float heights = ymax - ymin + 1.0f;
  float ctrx = xmin + 0.5f * (widths - 1.0f);
  float ctry = ymin + 0.5f * (heights - 1.0f);

  float pcx = d0 * widths + ctrx;
  float pcy = d1 * heights + ctry;
  float pw = expf(d2) * widths;
  float ph = expf(d3) * heights;

  float x1 = pcx - 0.5f * (pw - 1.0f);
  float y1 = pcy - 0.5f * (ph - 1.0f);
  float x2 = pcx + 0.5f * (pw - 1.0f);
  float y2 = pcy + 0.5f * (ph - 1.0f);

  float ow = (float)iminfo[1] - 1.0f;
  float oh = (float)iminfo[0] - 1.0f;
  x1 = fminf(fmaxf(x1, 0.0f), ow);
  x2 = fminf(fmaxf(x2, 0.0f), ow);
  y1 = fminf(fmaxf(y1, 0.0f), oh);
  y2 = fminf(fmaxf(y2, 0.0f), oh);

  float ws = x2 - x1 + 1.0f;
  float hs = y2 - y1 + 1.0f;
  bool keep = (score > THRESH_OBJ) && (ws >= 6.0f) && (hs >= 6.0f);

  boxes[r*4+0] = x1;
  boxes[r*4+1] = y1;
  boxes[r*4+2] = x2;
  boxes[r*4+3] = y2;
  sbits[r] = keep ? __float_as_uint(score) : 0u;
}

// ------ LDS histogram from sbits -> suffix scan -> base[], cnt; also zero fill[] ------
__global__ __launch_bounds__(1024) void k_scan(const u32* __restrict__ sbits,
    int* __restrict__ base, int* __restrict__ cnt, int* __restrict__ fill) {
  __shared__ int sh[NBUCK];
  __shared__ int ch[1024];
  int tid = threadIdx.x;
  for (int j = tid; j < NBUCK; j += 1024) { sh[j] = 0; fill[j] = 0; }
  __syncthreads();
  for (int j = tid; j < NB; j += 1024) {
    u32 bits = sbits[j];
    if (bits) { int b = min((int)((bits >> SH) - BLO), NBUCK - 1); atomicAdd(&sh[b], 1); }
  }
  __syncthreads();
  int c0 = sh[tid*5+0], c1 = sh[tid*5+1], c2 = sh[tid*5+2], c3 = sh[tid*5+3], c4 = sh[tid*5+4];
  ch[tid] = c0 + c1 + c2 + c3 + c4;
  __syncthreads();
  for (int off = 1; off < 1024; off <<= 1) {
    int v = ch[tid];
    int u = (tid + off < 1024) ? ch[tid + off] : 0;
    __syncthreads();
    ch[tid] = v + u;
    __syncthreads();
  }
  int S = (tid + 1 < 1024) ? ch[tid + 1] : 0;
  int b4 = S;
  int b3 = b4 + c4;
  int b2 = b3 + c3;
  int b1 = b2 + c2;
  int b0 = b1 + c1;
  base[tid*5+0] = b0; base[tid*5+1] = b1; base[tid*5+2] = b2;
  base[tid*5+3] = b3; base[tid*5+4] = b4;
  if (tid == 0) *cnt = ch[0];
}

// ---------------- place keys into bucket slots (order within bucket irrelevant) ----------------
__global__ __launch_bounds__(256) void k_place(const u32* __restrict__ sbits,
    const int* __restrict__ base, int* __restrict__ fill, u64* __restrict__ blist) {
  int i = blockIdx.x * 256 + threadIdx.x;
  if (i >= NB) return;
  u32 bits = sbits[i];
  if (!bits) return;
  int b = min((int)((bits >> SH) - BLO), NBUCK - 1);
  int pos = base[b] + atomicAdd(&fill[b], 1);
  blist[pos] = ((u64)bits << 32) | (u64)(0xFFFFFFFFu - (u32)i);
}

// ---------------- exact rank = base[b] + within-bucket greater-count; scatter ----------------
__global__ __launch_bounds__(256) void k_final(const u32* __restrict__ sbits,
    const int* __restrict__ base, const int* __restrict__ cnt,
    const u64* __restrict__ blist, const float* __restrict__ boxes,
    float* __restrict__ sboxes) {
  int i = blockIdx.x * 256 + threadIdx.x;
  if (i >= NB) return;
  u32 bits = sbits[i];
  if (!bits) return;
  int b = min((int)((bits >> SH) - BLO), NBUCK - 1);
  u64 key = ((u64)bits << 32) | (u64)(0xFFFFFFFFu - (u32)i);
  int s = base[b];
  int e = (b > 0) ? base[b-1] : *cnt;
  int r = s;
  for (int p = s; p < e; ++p) r += (blist[p] > key) ? 1 : 0;
  if (r < MAXC) ((float4*)sboxes)[r] = ((const float4*)boxes)[i];
}

// --- pairwise IoU bitmask; lower-tri zero-fill; diagonal blocks ALSO write compact diag[] ---
__global__ __launch_bounds__(64) void k_iou(const float* __restrict__ sboxes,
    const int* __restrict__ cnt, u64* __restrict__ mask, u64* __restrict__ diag) {
#pragma clang fp contract(off)
  int N = min(*cnt, MAXC);
  int bi = blockIdx.x, bj = blockIdx.y;
  int t = threadIdx.x;
  int i = bi * 64 + t;
  if (bj < bi) {                      // lower triangle: zero-fill so k_nms can OR whole rows
    if (i < N) mask[(size_t)i * NW + bj] = 0ULL;
    return;
  }
  if (bi * 64 >= N) return;
  __shared__ float4 jb[64];
  int j0 = bj * 64;
  if (j0 + t < N) jb[t] = ((const float4*)sboxes)[j0 + t];
  __syncthreads();
  if (i >= N) return;
  float4 a = ((const float4*)sboxes)[i];
  float areaA = (a.z - a.x + 1.0f) * (a.w - a.y + 1.0f);
  u64 word = 0;
  int jmax = min(64, N - j0);         // <=0 for pad word 79 -> writes 0
  for (int jj = 0; jj < jmax; ++jj) {
    int j = j0 + jj;
    if (j <= i) continue;
    float4 b = jb[jj];
    float iw = fminf(a.z, b.z) - fmaxf(a.x, b.x) + 1.0f;
    float ih = fminf(a.w, b.w) - fmaxf(a.y, b.y) + 1.0f;
    iw = fmaxf(iw, 0.0f);
    ih = fmaxf(ih, 0.0f);
    float inter = iw * ih;
    float areaB = (b.z - b.x + 1.0f) * (b.w - b.y + 1.0f);
    float iou = inter / (areaA + areaB - inter);
    if (iou > NMS_T) word |= (1ULL << jj);
  }
  mask[(size_t)i * NW + bj] = word;
  if (bi == bj) diag[i] = word;       // compact diagonal: coalesced column read in k_nms
}

// ---- serial greedy NMS (R18 form) + 3 helper waves warming the LOCAL L2 with the mask ----
__device__ __forceinline__ u64 rl64(u64 v, int l) {
  unsigned lo = __builtin_amdgcn_readlane((unsigned)(v & 0xffffffffULL), l);
  unsigned hi = __builtin_amdgcn_readlane((unsigned)(v >> 32), l);
  return ((u64)hi << 32) | (u64)lo;
}

__device__ __forceinline__ void gload_lds16(const void* g, void* l) {
  __builtin_amdgcn_global_load_lds(
      (const __attribute__((address_space(1))) unsigned int*)g,
      (__attribute__((address_space(3))) unsigned int*)l, 16, 0, 0);
}

__global__ __launch_bounds__(256, 1) void k_nms(const float* __restrict__ sboxes,
    const u64* __restrict__ mask, const u64* __restrict__ diag,
    const int* __restrict__ cnt, float* __restrict__ out) {
  const int tid = threadIdx.x;
  const int wv = tid >> 6;
  const int t = tid & 63;
  const int N = min(*cnt, MAXC);
  __shared__ int klist[TOPN + 1];          // slot TOPN = dump for predicated-off stores
  __shared__ __align__(16) u64 ring[13 * 128];  // 12 slots + dump slot 12 (1KB each)
  __shared__ int s_kept;

  if (wv > 0) {
    // ---- helper waves: stream mask (+diag) into THIS CU's L2, ascending row order ----
    float acc = 0.0f;
    if (wv == 1) {
      const float4* d4 = (const float4*)diag;          // 5056*8B = 2528 float4
      for (int i = t; i < 2528; i += 64) {
        float4 v = d4[i];
        acc += v.x + v.y + v.z + v.w;
      }
    }
    const float4* m4 = (const float4*)mask;            // NW*8/16 = 40 float4 per row
    size_t total = (size_t)N * 40;
    for (size_t i = (size_t)(wv - 1) * 64 + t; i < total; i += 192) {
      float4 v = m4[i];
      acc += v.x + v.y + v.z + v.w;
    }
    asm volatile("" :: "v"(acc));                      // keep loads live (rule #17)
    __syncthreads();                                   // matches wave 0's single barrier
    return;
  }

  // ---------------- wave 0: R18's serial NMS, byte-equivalent ----------------
  const int NBLK = (N + 63) >> 6;          // <= 79
  const int tt = (t < 40) ? t : 39;        // lane covers row bytes [16tt,16tt+16) = words 2tt,2tt+1
  const bool lane_ok = (t < 40);
  u64 rv0 = 0ULL, rv1 = 0ULL;              // remv: lane t owns words 2t, 2t+1 (t<40)
  int kept = 0;

  u64 colA = 0ULL, colB = 0ULL;            // ping-pong diagonal columns — coalesced
  if (NBLK > 0) colA = diag[t];
  int slot = 0;

#define FLUSHRING(n_) do { \
    asm volatile("s_waitcnt vmcnt(0)" ::: "memory"); \
    __builtin_amdgcn_sched_barrier(0); \
    int nf = (n_); \
    U2 q0  = *(const U2*)(ring + 0*128  + 2*tt); \
    U2 q1  = *(const U2*)(ring + 1*128  + 2*tt); \
    U2 q2  = *(const U2*)(ring + 2*128  + 2*tt); \
    U2 q3  = *(const U2*)(ring + 3*128  + 2*tt); \
    U2 q4  = *(const U2*)(ring + 4*128  + 2*tt); \
    U2 q5  = *(const U2*)(ring + 5*128  + 2*tt); \
    U2 q6  = *(const U2*)(ring + 6*128  + 2*tt); \
    U2 q7  = *(const U2*)(ring + 7*128  + 2*tt); \
    U2 q8  = *(const U2*)(ring + 8*128  + 2*tt); \
    U2 q9  = *(const U2*)(ring + 9*128  + 2*tt); \
    U2 q10 = *(const U2*)(ring + 10*128 + 2*tt); \
    U2 q11 = *(const U2*)(ring + 11*128 + 2*tt); \
    u64 o0 = 0, o1 = 0; \
    o0 |= (lane_ok && nf > 0)  ? q0.x  : 0ULL;  o1 |= (lane_ok && nf > 0)  ? q0.y  : 0ULL; \
    o0 |= (lane_ok && nf > 1)  ? q1.x  : 0ULL;  o1 |= (lane_ok && nf > 1)  ? q1.y  : 0ULL; \
    o0 |= (lane_ok && nf > 2)  ? q2.x  : 0ULL;  o1 |= (lane_ok && nf > 2)  ? q2.y  : 0ULL; \
    o0 |= (lane_ok && nf > 3)  ? q3.x  : 0ULL;  o1 |= (lane_ok && nf > 3)  ? q3.y  : 0ULL; \
    o0 |= (lane_ok && nf > 4)  ? q4.x  : 0ULL;  o1 |= (lane_ok && nf > 4)  ? q4.y  : 0ULL; \
    o0 |= (lane_ok && nf > 5)  ? q5.x  : 0ULL;  o1 |= (lane_ok && nf > 5)  ? q5.y  : 0ULL; \
    o0 |= (lane_ok && nf > 6)  ? q6.x  : 0ULL;  o1 |= (lane_ok && nf > 6)  ? q6.y  : 0ULL; \
    o0 |= (lane_ok && nf > 7)  ? q7.x  : 0ULL;  o1 |= (lane_ok && nf > 7)  ? q7.y  : 0ULL; \
    o0 |= (lane_ok && nf > 8)  ? q8.x  : 0ULL;  o1 |= (lane_ok && nf > 8)  ? q8.y  : 0ULL; \
    o0 |= (lane_ok && nf > 9)  ? q9.x  : 0ULL;  o1 |= (lane_ok && nf > 9)  ? q9.y  : 0ULL; \
    o0 |= (lane_ok && nf > 10) ? q10.x : 0ULL;  o1 |= (lane_ok && nf > 10) ? q10.y : 0ULL; \
    o0 |= (lane_ok && nf > 11) ? q11.x : 0ULL;  o1 |= (lane_ok && nf > 11) ? q11.y : 0ULL; \
    rv0 |= o0; rv1 |= o1; \
  } while (0)

  for (int b = 0; b < NBLK; ++b) {
    u64 cc = (b & 1) ? colB : colA;
    if (slot > 0) { FLUSHRING(slot); slot = 0; }
    int base = b * 64;
    u64 w = rl64((b & 1) ? rv1 : rv0, b >> 1);
    int nv = N - base; if (nv > 64) nv = 64;
    u64 valid = (nv >= 64) ? ~0ULL : ((1ULL << nv) - 1ULL);
    u64 avail = ~w & valid;
    if (b + 1 < NBLK) {
      u64 nx = diag[(b + 1) * 64 + t];
      if (b & 1) colA = nx; else colB = nx;
    }
    // predicated 4x-unrolled scan: branch-free ALU + one stage issue per kept
    while (avail && kept < TOPN) {
#pragma unroll
      for (int u = 0; u < 4; ++u) {
        bool on = (avail != 0ULL) && (kept < TOPN);
        int d = (int)__builtin_ctzll(avail | (1ULL << 63));  // d in [0,63]
        int row = base + d;
        klist[on ? kept : TOPN] = row;                       // all lanes, same addr+value
        gload_lds16((const char*)(mask + (size_t)row * NW) + (size_t)tt * 16,
                    (void*)(ring + (size_t)(on ? slot : 12) * 128));
        u64 sup = rl64(cc, d);
        u64 clear = on ? (sup | (1ULL << d)) : 0ULL;
        avail &= ~clear;
        kept += on ? 1 : 0;
        slot += on ? 1 : 0;
      }
      if (slot >= 8) { FLUSHRING(slot); slot = 0; }          // slot <= 11
    }
    if (kept >= TOPN) break;
  }
  if (t == 0) s_kept = kept;
  __syncthreads();
  kept = s_kept;
  // epilogue (wave 0 only): write the FULL 300x5 output (zeros where unfilled)
  for (int e = t; e < TOPN * 5; e += 64) {
    int row = e / 5, col = e % 5;
    float v = 0.0f;
    if (col > 0 && row < kept) v = sboxes[klist[row] * 4 + (col - 1)];
    out[e] = v;
  }
#undef FLUSHRING
}

extern "C" void kernel_launch(void* const* d_in, const int* in_sizes, int n_in,
                              void* d_out, int out_size, void* d_ws, size_t ws_size,
                              hipStream_t stream) {
  const float* cls  = (const float*)d_in[0];
  const float* pred = (const float*)d_in[1];
  const int*   imi  = (const int*)d_in[2];
  const float* mean = (const float*)d_in[3];
  const float* stdv = (const float*)d_in[4];
  float* out = (float*)d_out;

  char* ws = (char*)d_ws;
  float* boxes  = (float*)(ws);                        // NB*4 floats   = 277440 B
  u32*   sbits  = (u32*)(ws + 277440);                 // NB u32        = 69360 B
  float* sboxes = (float*)(ws + 346800);               // MAXC*4 floats = 80000 B
  int*   cnt    = (int*)(ws + 426800);                 // 16 B
  int*   fill   = (int*)(ws + 447296);                 // NBUCK ints    = 20480 B
  int*   base   = (int*)(ws + 467776);                 // NBUCK ints    = 20480 B
  u64*   mask   = (u64*)(ws + 488256);                 // NRALLOC*NW*8  = 3235840 B
  u64*   blist  = mask;   // alias: blist (<=138720 B) dead before k_iou writes mask
  u64*   diag   = (u64*)(ws + 426816);  // 40448 B; overlaps fill region (fill dead after k_place)

  k_decode<<<(NB + 255) / 256, 256, 0, stream>>>(cls, pred, imi, mean, stdv, boxes, sbits);
  k_scan<<<1, 1024, 0, stream>>>(sbits, base, cnt, fill);
  k_place<<<(NB + 255) / 256, 256, 0, stream>>>(sbits, base, fill, blist);
  k_final<<<(NB + 255) / 256, 256, 0, stream>>>(sbits, base, cnt, blist, boxes, sboxes);
  dim3 giou((MAXC + 63) / 64, NW);
  k_iou<<<giou, 64, 0, stream>>>(sboxes, cnt, mask, diag);
  k_nms<<<1, 256, 0, stream>>>(sboxes, mask, diag, cnt, out);
}

// Round 23
// 96.490 us; speedup vs baseline: 3.5729x; 3.5729x over previous
//
#include <hip/hip_runtime.h>

#define NA 15
#define GH 34
#define GW 34
#define SP (GH*GW)          // 1156
#define NB (SP*NA)          // 17340
#define MAXC 5000
#define TOPN 300
#define NW 80               // padded words per mask row (79 used + 1 pad)
#define NRALLOC 5056        // mask rows allocated
#define THRESH_OBJ 0.2f
#define NMS_T 0.7f
// score-bucket constants: positive-float bits are order-preserving
#define SH 12
#define BLO 0x3E4CCu        // bits(0.2f) >> 12
#define NBUCK 5120          // covers bits(1.0)>>12 - BLO = 4916, 5 per scan-thread

typedef unsigned long long u64;
typedef unsigned int u32;
struct __align__(16) U2 { u64 x, y; };

__constant__ float c_aw[NA] = {45.3f,32.0f,22.6f,90.5f,64.0f,45.3f,181.0f,128.0f,90.5f,271.5f,192.0f,135.8f,362.0f,256.0f,181.0f};
__constant__ float c_ah[NA] = {22.6f,32.0f,45.3f,45.3f,64.0f,90.5f,90.5f,128.0f,181.0f,135.8f,192.0f,271.5f,181.0f,256.0f,362.0f};

// ---------------- decode: anchors + deltas -> proposals + score bits ----------------
__global__ __launch_bounds__(256) void k_decode(
    const float* __restrict__ cls, const float* __restrict__ pred,
    const int* __restrict__ iminfo, const float* __restrict__ mean,
    const float* __restrict__ stdv, float* __restrict__ boxes,
    u32* __restrict__ sbits) {
#pragma clang fp contract(off)
  int r = blockIdx.x * 256 + threadIdx.x;
  if (r >= NB) return;
  int n = r % NA;
  int p = r / NA;       // p = h*GW + w
  int w = p % GW;
  int h = p / GW;

  float score = cls[(NA + n) * SP + p];             // channel NA+n, spatial p

  float d0 = pred[(n*4+0)*SP + p] * stdv[0] + mean[0];
  float d1 = pred[(n*4+1)*SP + p] * stdv[1] + mean[1];
  float d2 = pred[(n*4+2)*SP + p] * stdv[2] + mean[2];
  float d3 = pred[(n*4+3)*SP + p] * stdv[3] + mean[3];

  float aw = c_aw[n], ah = c_ah[n];
  float sx = (float)(w * 16);
  float sy = (float)(h * 16);
  float xmin = -0.5f * (aw - 1.0f) + sx;
  float ymin = -0.5f * (ah - 1.0f) + sy;
  float xmax =  0.5f * (aw - 1.0f) + sx;
  float ymax =  0.5f * (ah - 1.0f) + sy;

  float widths  = xmax - xmin + 1.0f;
  float heights = ymax - ymin + 1.0f;
  float ctrx = xmin + 0.5f * (widths - 1.0f);
  float ctry = ymin + 0.5f * (heights - 1.0f);

  float pcx = d0 * widths + ctrx;
  float pcy = d1 * heights + ctry;
  float pw = expf(d2) * widths;
  float ph = expf(d3) * heights;

  float x1 = pcx - 0.5f * (pw - 1.0f);
  float y1 = pcy - 0.5f * (ph - 1.0f);
  float x2 = pcx + 0.5f * (pw - 1.0f);
  float y2 = pcy + 0.5f * (ph - 1.0f);

  float ow = (float)iminfo[1] - 1.0f;
  float oh = (float)iminfo[0] - 1.0f;
  x1 = fminf(fmaxf(x1, 0.0f), ow);
  x2 = fminf(fmaxf(x2, 0.0f), ow);
  y1 = fminf(fmaxf(y1, 0.0f), oh);
  y2 = fminf(fmaxf(y2, 0.0f), oh);

  float ws = x2 - x1 + 1.0f;
  float hs = y2 - y1 + 1.0f;
  bool keep = (score > THRESH_OBJ) && (ws >= 6.0f) && (hs >= 6.0f);

  boxes[r*4+0] = x1;
  boxes[r*4+1] = y1;
  boxes[r*4+2] = x2;
  boxes[r*4+3] = y2;
  sbits[r] = keep ? __float_as_uint(score) : 0u;
}

// ------ LDS histogram from sbits -> suffix scan -> base[], cnt; also zero fill[] ------
__global__ __launch_bounds__(1024) void k_scan(const u32* __restrict__ sbits,
    int* __restrict__ base, int* __restrict__ cnt, int* __restrict__ fill) {
  __shared__ int sh[NBUCK];
  __shared__ int ch[1024];
  int tid = threadIdx.x;
  for (int j = tid; j < NBUCK; j += 1024) { sh[j] = 0; fill[j] = 0; }
  __syncthreads();
  for (int j = tid; j < NB; j += 1024) {
    u32 bits = sbits[j];
    if (bits) { int b = min((int)((bits >> SH) - BLO), NBUCK - 1); atomicAdd(&sh[b], 1); }
  }
  __syncthreads();
  int c0 = sh[tid*5+0], c1 = sh[tid*5+1], c2 = sh[tid*5+2], c3 = sh[tid*5+3], c4 = sh[tid*5+4];
  ch[tid] = c0 + c1 + c2 + c3 + c4;
  __syncthreads();
  for (int off = 1; off < 1024; off <<= 1) {
    int v = ch[tid];
    int u = (tid + off < 1024) ? ch[tid + off] : 0;
    __syncthreads();
    ch[tid] = v + u;
    __syncthreads();
  }
  int S = (tid + 1 < 1024) ? ch[tid + 1] : 0;
  int b4 = S;
  int b3 = b4 + c4;
  int b2 = b3 + c3;
  int b1 = b2 + c2;
  int b0 = b1 + c1;
  base[tid*5+0] = b0; base[tid*5+1] = b1; base[tid*5+2] = b2;
  base[tid*5+3] = b3; base[tid*5+4] = b4;
  if (tid == 0) *cnt = ch[0];
}

// ---------------- place keys into bucket slots (order within bucket irrelevant) ----------------
__global__ __launch_bounds__(256) void k_place(const u32* __restrict__ sbits,
    const int* __restrict__ base, int* __restrict__ fill, u64* __restrict__ blist) {
  int i = blockIdx.x * 256 + threadIdx.x;
  if (i >= NB) return;
  u32 bits = sbits[i];
  if (!bits) return;
  int b = min((int)((bits >> SH) - BLO), NBUCK - 1);
  int pos = base[b] + atomicAdd(&fill[b], 1);
  blist[pos] = ((u64)bits << 32) | (u64)(0xFFFFFFFFu - (u32)i);
}

// ---------------- exact rank = base[b] + within-bucket greater-count; scatter ----------------
__global__ __launch_bounds__(256) void k_final(const u32* __restrict__ sbits,
    const int* __restrict__ base, const int* __restrict__ cnt,
    const u64* __restrict__ blist, const float* __restrict__ boxes,
    float* __restrict__ sboxes) {
  int i = blockIdx.x * 256 + threadIdx.x;
  if (i >= NB) return;
  u32 bits = sbits[i];
  if (!bits) return;
  int b = min((int)((bits >> SH) - BLO), NBUCK - 1);
  u64 key = ((u64)bits << 32) | (u64)(0xFFFFFFFFu - (u32)i);
  int s = base[b];
  int e = (b > 0) ? base[b-1] : *cnt;
  int r = s;
  for (int p = s; p < e; ++p) r += (blist[p] > key) ? 1 : 0;
  if (r < MAXC) ((float4*)sboxes)[r] = ((const float4*)boxes)[i];
}

// --- pairwise IoU bitmask; lower-tri zero-fill; diagonal blocks ALSO write compact diag[] ---
__global__ __launch_bounds__(64) void k_iou(const float* __restrict__ sboxes,
    const int* __restrict__ cnt, u64* __restrict__ mask, u64* __restrict__ diag) {
#pragma clang fp contract(off)
  int N = min(*cnt, MAXC);
  int bi = blockIdx.x, bj = blockIdx.y;
  int t = threadIdx.x;
  int i = bi * 64 + t;
  if (bj < bi) {                      // lower triangle: zero-fill so k_nms can OR whole rows
    if (i < N) mask[(size_t)i * NW + bj] = 0ULL;
    return;
  }
  if (bi * 64 >= N) return;
  __shared__ float4 jb[64];
  int j0 = bj * 64;
  if (j0 + t < N) jb[t] = ((const float4*)sboxes)[j0 + t];
  __syncthreads();
  if (i >= N) return;
  float4 a = ((const float4*)sboxes)[i];
  float areaA = (a.z - a.x + 1.0f) * (a.w - a.y + 1.0f);
  u64 word = 0;
  int jmax = min(64, N - j0);         // <=0 for pad word 79 -> writes 0
  for (int jj = 0; jj < jmax; ++jj) {
    int j = j0 + jj;
    if (j <= i) continue;
    float4 b = jb[jj];
    float iw = fminf(a.z, b.z) - fmaxf(a.x, b.x) + 1.0f;
    float ih = fminf(a.w, b.w) - fmaxf(a.y, b.y) + 1.0f;
    iw = fmaxf(iw, 0.0f);
    ih = fmaxf(ih, 0.0f);
    float inter = iw * ih;
    float areaB = (b.z - b.x + 1.0f) * (b.w - b.y + 1.0f);
    float iou = inter / (areaA + areaB - inter);
    if (iou > NMS_T) word |= (1ULL << jj);
  }
  mask[(size_t)i * NW + bj] = word;
  if (bi == bj) diag[i] = word;       // compact diagonal: coalesced column read in k_nms
}

// ---- serial greedy NMS: coalesced diag column + predicated scan + issue-on-keep staging ----
__device__ __forceinline__ u64 rl64(u64 v, int l) {
  unsigned lo = __builtin_amdgcn_readlane((unsigned)(v & 0xffffffffULL), l);
  unsigned hi = __builtin_amdgcn_readlane((unsigned)(v >> 32), l);
  return ((u64)hi << 32) | (u64)lo;
}

__device__ __forceinline__ void gload_lds16(const void* g, void* l) {
  __builtin_amdgcn_global_load_lds(
      (const __attribute__((address_space(1))) unsigned int*)g,
      (__attribute__((address_space(3))) unsigned int*)l, 16, 0, 0);
}

__global__ __launch_bounds__(64, 1) void k_nms(const float* __restrict__ sboxes,
    const u64* __restrict__ mask, const u64* __restrict__ diag,
    const int* __restrict__ cnt, float* __restrict__ out) {
  const int t = threadIdx.x;
  const int N = min(*cnt, MAXC);
  const int NBLK = (N + 63) >> 6;          // <= 79
  const int tt = (t < 40) ? t : 39;        // lane covers row bytes [16tt,16tt+16) = words 2tt,2tt+1
  const bool lane_ok = (t < 40);
  u64 rv0 = 0ULL, rv1 = 0ULL;              // remv: lane t owns words 2t, 2t+1 (t<40)
  __shared__ int klist[TOPN + 1];          // slot TOPN = dump for predicated-off stores
  __shared__ __align__(16) u64 ring[13 * 128];  // 12 slots + dump slot 12 (1KB each)
  int kept = 0;

  u64 colA = 0ULL, colB = 0ULL;            // ping-pong diagonal columns — coalesced loads
  if (NBLK > 0) colA = diag[t];
  int pslot = 0;                           // pending ring entries from previous block

  // flush nf pending ring slots into rv0/rv1 — rows fully valid, no indices needed
#define FLUSHRING(n_) do { \
    asm volatile("s_waitcnt vmcnt(0)" ::: "memory"); \
    __builtin_amdgcn_sched_barrier(0); \
    int nf = (n_); \
    U2 q0  = *(const U2*)(ring + 0*128  + 2*tt); \
    U2 q1  = *(const U2*)(ring + 1*128  + 2*tt); \
    U2 q2  = *(const U2*)(ring + 2*128  + 2*tt); \
    U2 q3  = *(const U2*)(ring + 3*128  + 2*tt); \
    U2 q4  = *(const U2*)(ring + 4*128  + 2*tt); \
    U2 q5  = *(const U2*)(ring + 5*128  + 2*tt); \
    U2 q6  = *(const U2*)(ring + 6*128  + 2*tt); \
    U2 q7  = *(const U2*)(ring + 7*128  + 2*tt); \
    U2 q8  = *(const U2*)(ring + 8*128  + 2*tt); \
    U2 q9  = *(const U2*)(ring + 9*128  + 2*tt); \
    U2 q10 = *(const U2*)(ring + 10*128 + 2*tt); \
    U2 q11 = *(const U2*)(ring + 11*128 + 2*tt); \
    u64 o0 = 0, o1 = 0; \
    o0 |= (lane_ok && nf > 0)  ? q0.x  : 0ULL;  o1 |= (lane_ok && nf > 0)  ? q0.y  : 0ULL; \
    o0 |= (lane_ok && nf > 1)  ? q1.x  : 0ULL;  o1 |= (lane_ok && nf > 1)  ? q1.y  : 0ULL; \
    o0 |= (lane_ok && nf > 2)  ? q2.x  : 0ULL;  o1 |= (lane_ok && nf > 2)  ? q2.y  : 0ULL; \
    o0 |= (lane_ok && nf > 3)  ? q3.x  : 0ULL;  o1 |= (lane_ok && nf > 3)  ? q3.y  : 0ULL; \
    o0 |= (lane_ok && nf > 4)  ? q4.x  : 0ULL;  o1 |= (lane_ok && nf > 4)  ? q4.y  : 0ULL; \
    o0 |= (lane_ok && nf > 5)  ? q5.x  : 0ULL;  o1 |= (lane_ok && nf > 5)  ? q5.y  : 0ULL; \
    o0 |= (lane_ok && nf > 6)  ? q6.x  : 0ULL;  o1 |= (lane_ok && nf > 6)  ? q6.y  : 0ULL; \
    o0 |= (lane_ok && nf > 7)  ? q7.x  : 0ULL;  o1 |= (lane_ok && nf > 7)  ? q7.y  : 0ULL; \
    o0 |= (lane_ok && nf > 8)  ? q8.x  : 0ULL;  o1 |= (lane_ok && nf > 8)  ? q8.y  : 0ULL; \
    o0 |= (lane_ok && nf > 9)  ? q9.x  : 0ULL;  o1 |= (lane_ok && nf > 9)  ? q9.y  : 0ULL; \
    o0 |= (lane_ok && nf > 10) ? q10.x : 0ULL;  o1 |= (lane_ok && nf > 10) ? q10.y : 0ULL; \
    o0 |= (lane_ok && nf > 11) ? q11.x : 0ULL;  o1 |= (lane_ok && nf > 11) ? q11.y : 0ULL; \
    rv0 |= o0; rv1 |= o1; \
  } while (0)

  for (int b = 0; b < NBLK; ++b) {
    u64 cc = (b & 1) ? colB : colA;
    // deferred flush of previous block's kept rows (stages issued ~a block ago — latency mostly hidden)
    if (pslot > 0) { FLUSHRING(pslot); pslot = 0; }
    int base = b * 64;
    // carry-in from all previously-kept rows (word b lives on lane b>>1, slot b&1)
    u64 w = rl64((b & 1) ? rv1 : rv0, b >> 1);
    int nv = N - base; if (nv > 64) nv = 64;
    u64 valid = (nv >= 64) ? ~0ULL : ((1ULL << nv) - 1ULL);
    u64 avail = ~w & valid;
    // prefetch next block's diagonal column — single coalesced 512B transaction
    if (b + 1 < NBLK) {
      u64 nx = diag[(b + 1) * 64 + t];
      if (b & 1) colA = nx; else colB = nx;
    }
    int slot = 0;
    // predicated 4x-unrolled scan: every sub-iteration is branch-free ALU + one stage issue
    while (avail && kept < TOPN) {
#pragma unroll
      for (int u = 0; u < 4; ++u) {
        bool on = (avail != 0ULL) && (kept < TOPN);
        int d = (int)__builtin_ctzll(avail | (1ULL << 63));  // d in [0,63]
        int row = base + d;
        klist[on ? kept : TOPN] = row;                       // all lanes, same addr+value
        // stage full mask row into ring (off-iterations -> dump slot 12; no same-slot races)
        gload_lds16((const char*)(mask + (size_t)row * NW) + (size_t)tt * 16,
                    (void*)(ring + (size_t)(on ? slot : 12) * 128));
        u64 sup = rl64(cc, d);
        u64 clear = on ? (sup | (1ULL << d)) : 0ULL;
        avail &= ~clear;
        kept += on ? 1 : 0;
        slot += on ? 1 : 0;
      }
      if (slot >= 8) { FLUSHRING(slot); slot = 0; }          // slot <= 11; rare (block keeps >=8)
    }
    if (kept >= TOPN) break;                                 // remaining drain is dead work
    pslot = slot;
  }
  __syncthreads();
  // epilogue: write the FULL 300x5 output (zeros where unfilled)
  for (int e = t; e < TOPN * 5; e += 64) {
    int row = e / 5, col = e % 5;
    float v = 0.0f;
    if (col > 0 && row < kept) v = sboxes[klist[row] * 4 + (col - 1)];
    out[e] = v;
  }
#undef FLUSHRING
}

extern "C" void kernel_launch(void* const* d_in, const int* in_sizes, int n_in,
                              void* d_out, int out_size, void* d_ws, size_t ws_size,
                              hipStream_t stream) {
  const float* cls  = (const float*)d_in[0];
  const float* pred = (const float*)d_in[1];
  const int*   imi  = (const int*)d_in[2];
  const float* mean = (const float*)d_in[3];
  const float* stdv = (const float*)d_in[4];
  float* out = (float*)d_out;

  char* ws = (char*)d_ws;
  float* boxes  = (float*)(ws);                        // NB*4 floats   = 277440 B
  u32*   sbits  = (u32*)(ws + 277440);                 // NB u32        = 69360 B
  float* sboxes = (float*)(ws + 346800);               // MAXC*4 floats = 80000 B
  int*   cnt    = (int*)(ws + 426800);                 // 16 B
  int*   fill   = (int*)(ws + 447296);                 // NBUCK ints    = 20480 B
  int*   base   = (int*)(ws + 467776);                 // NBUCK ints    = 20480 B
  u64*   mask   = (u64*)(ws + 488256);                 // NRALLOC*NW*8  = 3235840 B
  u64*   blist  = mask;   // alias: blist (<=138720 B) dead before k_iou writes mask
  u64*   diag   = (u64*)(ws + 426816);  // 40448 B; overlaps fill region (fill dead after k_place)

  k_decode<<<(NB + 255) / 256, 256, 0, stream>>>(cls, pred, imi, mean, stdv, boxes, sbits);
  k_scan<<<1, 1024, 0, stream>>>(sbits, base, cnt, fill);
  k_place<<<(NB + 255) / 256, 256, 0, stream>>>(sbits, base, fill, blist);
  k_final<<<(NB + 255) / 256, 256, 0, stream>>>(sbits, base, cnt, blist, boxes, sboxes);
  dim3 giou((MAXC + 63) / 64, NW);
  k_iou<<<giou, 64, 0, stream>>>(sboxes, cnt, mask, diag);
  k_nms<<<1, 64, 0, stream>>>(sboxes, mask, diag, cnt, out);
}

// Round 24
// 94.823 us; speedup vs baseline: 3.6357x; 1.0176x over previous
//
#include <hip/hip_runtime.h>

#define NA 15
#define GH 34
#define GW 34
#define SP (GH*GW)          // 1156
#define NB (SP*NA)          // 17340
#define MAXC 5000
#define TOPN 300
#define NW 80               // padded words per mask row (79 used + 1 pad)
#define NRALLOC 5056        // mask rows allocated
#define THRESH_OBJ 0.2f
#define NMS_T 0.7f
// score-bucket constants: positive-float bits are order-preserving
#define SH 12
#define BLO 0x3E4CCu        // bits(0.2f) >> 12
#define NBUCK 5120          // covers bits(1.0)>>12 - BLO = 4916, 5 per scan-thread

typedef unsigned long long u64;
typedef unsigned int u32;
struct __align__(16) U2 { u64 x, y; };

__constant__ float c_aw[NA] = {45.3f,32.0f,22.6f,90.5f,64.0f,45.3f,181.0f,128.0f,90.5f,271.5f,192.0f,135.8f,362.0f,256.0f,181.0f};
__constant__ float c_ah[NA] = {22.6f,32.0f,45.3f,45.3f,64.0f,90.5f,90.5f,128.0f,181.0f,135.8f,192.0f,271.5f,181.0f,256.0f,362.0f};

// ---------------- decode: anchors + deltas -> proposals + score bits + global histogram ----------------
__global__ __launch_bounds__(256) void k_decode(
    const float* __restrict__ cls, const float* __restrict__ pred,
    const int* __restrict__ iminfo, const float* __restrict__ mean,
    const float* __restrict__ stdv, float* __restrict__ boxes,
    u32* __restrict__ sbits, int* __restrict__ hist) {
#pragma clang fp contract(off)
  int r = blockIdx.x * 256 + threadIdx.x;
  if (r >= NB) return;
  int n = r % NA;
  int p = r / NA;       // p = h*GW + w
  int w = p % GW;
  int h = p / GW;

  float score = cls[(NA + n) * SP + p];             // channel NA+n, spatial p

  float d0 = pred[(n*4+0)*SP + p] * stdv[0] + mean[0];
  float d1 = pred[(n*4+1)*SP + p] * stdv[1] + mean[1];
  float d2 = pred[(n*4+2)*SP + p] * stdv[2] + mean[2];
  float d3 = pred[(n*4+3)*SP + p] * stdv[3] + mean[3];

  float aw = c_aw[n], ah = c_ah[n];
  float sx = (float)(w * 16);
  float sy = (float)(h * 16);
  float xmin = -0.5f * (aw - 1.0f) + sx;
  float ymin = -0.5f * (ah - 1.0f) + sy;
  float xmax =  0.5f * (aw - 1.0f) + sx;
  float ymax =  0.5f * (ah - 1.0f) + sy;

  float widths  = xmax - xmin + 1.0f;
  float heights = ymax - ymin + 1.0f;
  float ctrx = xmin + 0.5f * (widths - 1.0f);
  float ctry = ymin + 0.5f * (heights - 1.0f);

  float pcx = d0 * widths + ctrx;
  float pcy = d1 * heights + ctry;
  float pw = expf(d2) * widths;
  float ph = expf(d3) * heights;

  float x1 = pcx - 0.5f * (pw - 1.0f);
  float y1 = pcy - 0.5f * (ph - 1.0f);
  float x2 = pcx + 0.5f * (pw - 1.0f);
  float y2 = pcy + 0.5f * (ph - 1.0f);

  float ow = (float)iminfo[1] - 1.0f;
  float oh = (float)iminfo[0] - 1.0f;
  x1 = fminf(fmaxf(x1, 0.0f), ow);
  x2 = fminf(fmaxf(x2, 0.0f), ow);
  y1 = fminf(fmaxf(y1, 0.0f), oh);
  y2 = fminf(fmaxf(y2, 0.0f), oh);

  float ws = x2 - x1 + 1.0f;
  float hs = y2 - y1 + 1.0f;
  bool keep = (score > THRESH_OBJ) && (ws >= 6.0f) && (hs >= 6.0f);

  boxes[r*4+0] = x1;
  boxes[r*4+1] = y1;
  boxes[r*4+2] = x2;
  boxes[r*4+3] = y2;
  u32 bits = keep ? __float_as_uint(score) : 0u;
  sbits[r] = bits;
  if (bits) {
    int b = min((int)((bits >> SH) - BLO), NBUCK - 1);
    atomicAdd(&hist[b], 1);
  }
}

// ---------------- suffix-scan of bucket histogram: base[b] = #elems in buckets > b ----------------
__global__ __launch_bounds__(1024) void k_scan(const int* __restrict__ hist,
    int* __restrict__ base, int* __restrict__ cnt) {
  __shared__ int sh[NBUCK];
  __shared__ int ch[1024];
  int tid = threadIdx.x;
  for (int j = tid; j < NBUCK; j += 1024) sh[j] = hist[j];
  __syncthreads();
  int c0 = sh[tid*5+0], c1 = sh[tid*5+1], c2 = sh[tid*5+2], c3 = sh[tid*5+3], c4 = sh[tid*5+4];
  ch[tid] = c0 + c1 + c2 + c3 + c4;
  __syncthreads();
  for (int off = 1; off < 1024; off <<= 1) {
    int v = ch[tid];
    int u = (tid + off < 1024) ? ch[tid + off] : 0;
    __syncthreads();
    ch[tid] = v + u;
    __syncthreads();
  }
  int S = (tid + 1 < 1024) ? ch[tid + 1] : 0;
  int b4 = S;
  int b3 = b4 + c4;
  int b2 = b3 + c3;
  int b1 = b2 + c2;
  int b0 = b1 + c1;
  base[tid*5+0] = b0; base[tid*5+1] = b1; base[tid*5+2] = b2;
  base[tid*5+3] = b3; base[tid*5+4] = b4;
  if (tid == 0) *cnt = ch[0];
}

// ---------------- place keys into bucket slots (order within bucket irrelevant) ----------------
__global__ __launch_bounds__(256) void k_place(const u32* __restrict__ sbits,
    const int* __restrict__ base, int* __restrict__ fill, u64* __restrict__ blist) {
  int i = blockIdx.x * 256 + threadIdx.x;
  if (i >= NB) return;
  u32 bits = sbits[i];
  if (!bits) return;
  int b = min((int)((bits >> SH) - BLO), NBUCK - 1);
  int pos = base[b] + atomicAdd(&fill[b], 1);
  blist[pos] = ((u64)bits << 32) | (u64)(0xFFFFFFFFu - (u32)i);
}

// ---------------- exact rank = base[b] + within-bucket greater-count; scatter ----------------
__global__ __launch_bounds__(256) void k_final(const u32* __restrict__ sbits,
    const int* __restrict__ base, const int* __restrict__ cnt,
    const u64* __restrict__ blist, const float* __restrict__ boxes,
    float* __restrict__ sboxes) {
  int i = blockIdx.x * 256 + threadIdx.x;
  if (i >= NB) return;
  u32 bits = sbits[i];
  if (!bits) return;
  int b = min((int)((bits >> SH) - BLO), NBUCK - 1);
  u64 key = ((u64)bits << 32) | (u64)(0xFFFFFFFFu - (u32)i);
  int s = base[b];
  int e = (b > 0) ? base[b-1] : *cnt;
  int r = s;
  for (int p = s; p < e; ++p) r += (blist[p] > key) ? 1 : 0;
  if (r < MAXC) ((float4*)sboxes)[r] = ((const float4*)boxes)[i];
}

// --- pairwise IoU bitmask, UPPER-TRI ONLY (no zero-fill); diagonal blocks write diag[] ---
__global__ __launch_bounds__(64) void k_iou(const float* __restrict__ sboxes,
    const int* __restrict__ cnt, u64* __restrict__ mask, u64* __restrict__ diag) {
#pragma clang fp contract(off)
  int N = min(*cnt, MAXC);
  int bi = blockIdx.x, bj = blockIdx.y;
  if (bj < bi) return;                // k_nms masks unwritten lower-tri words by block index
  int t = threadIdx.x;
  int i = bi * 64 + t;
  if (bi * 64 >= N) return;
  __shared__ float4 jb[64];
  int j0 = bj * 64;
  if (j0 + t < N) jb[t] = ((const float4*)sboxes)[j0 + t];
  __syncthreads();
  if (i >= N) return;
  float4 a = ((const float4*)sboxes)[i];
  float areaA = (a.z - a.x + 1.0f) * (a.w - a.y + 1.0f);
  u64 word = 0;
  int jmax = min(64, N - j0);         // <=0 for pad word 79 -> writes 0
  for (int jj = 0; jj < jmax; ++jj) {
    int j = j0 + jj;
    if (j <= i) continue;
    float4 b = jb[jj];
    float iw = fminf(a.z, b.z) - fmaxf(a.x, b.x) + 1.0f;
    float ih = fminf(a.w, b.w) - fmaxf(a.y, b.y) + 1.0f;
    iw = fmaxf(iw, 0.0f);
    ih = fmaxf(ih, 0.0f);
    float inter = iw * ih;
    float areaB = (b.z - b.x + 1.0f) * (b.w - b.y + 1.0f);
    float iou = inter / (areaA + areaB - inter);
    if (iou > NMS_T) word |= (1ULL << jj);
  }
  mask[(size_t)i * NW + bj] = word;
  if (bi == bj) diag[i] = word;       // compact diagonal: coalesced column read in k_nms
}

// ---- serial greedy NMS: diag column + predicated scan + issue-on-keep staging;
// ---- flush masks lower-tri junk with a WAVE-UNIFORM block-index compare (no per-row data) ----
__device__ __forceinline__ u64 rl64(u64 v, int l) {
  unsigned lo = __builtin_amdgcn_readlane((unsigned)(v & 0xffffffffULL), l);
  unsigned hi = __builtin_amdgcn_readlane((unsigned)(v >> 32), l);
  return ((u64)hi << 32) | (u64)lo;
}

__device__ __forceinline__ void gload_lds16(const void* g, void* l) {
  __builtin_amdgcn_global_load_lds(
      (const __attribute__((address_space(1))) unsigned int*)g,
      (__attribute__((address_space(3))) unsigned int*)l, 16, 0, 0);
}

__global__ __launch_bounds__(64, 1) void k_nms(const float* __restrict__ sboxes,
    const u64* __restrict__ mask, const u64* __restrict__ diag,
    const int* __restrict__ cnt, float* __restrict__ out) {
  const int t = threadIdx.x;
  const int N = min(*cnt, MAXC);
  const int NBLK = (N + 63) >> 6;          // <= 79
  const int tt = (t < 40) ? t : 39;        // lane covers row bytes [16tt,16tt+16) = words 2tt,2tt+1
  const bool lane_ok = (t < 40);
  const int w0i = 2 * tt, w1i = 2 * tt + 1;
  u64 rv0 = 0ULL, rv1 = 0ULL;              // remv: lane t owns words 2t, 2t+1 (t<40)
  __shared__ int klist[TOPN + 1];          // slot TOPN = dump for predicated-off stores
  __shared__ __align__(16) u64 ring[13 * 128];  // 12 slots + dump slot 12 (1KB each)
  int kept = 0;

  u64 colA = 0ULL, colB = 0ULL;            // ping-pong diagonal columns — coalesced loads
  if (NBLK > 0) colA = diag[t];
  int pslot = 0;                           // pending ring entries from previous block
  int pblk = 0;                            // block index of pending rows

  // flush nf pending ring slots (rows all from block bq_) into rv0/rv1.
  // words < bq are unwritten junk -> masked by wave-uniform compare (m0/m1).
#define FLUSHRING(n_, bq_) do { \
    asm volatile("s_waitcnt vmcnt(0)" ::: "memory"); \
    __builtin_amdgcn_sched_barrier(0); \
    int nf = (n_); int bq = (bq_); \
    bool m0 = lane_ok && (w0i >= bq); \
    bool m1 = lane_ok && (w1i >= bq); \
    U2 q0  = *(const U2*)(ring + 0*128  + 2*tt); \
    U2 q1  = *(const U2*)(ring + 1*128  + 2*tt); \
    U2 q2  = *(const U2*)(ring + 2*128  + 2*tt); \
    U2 q3  = *(const U2*)(ring + 3*128  + 2*tt); \
    U2 q4  = *(const U2*)(ring + 4*128  + 2*tt); \
    U2 q5  = *(const U2*)(ring + 5*128  + 2*tt); \
    U2 q6  = *(const U2*)(ring + 6*128  + 2*tt); \
    U2 q7  = *(const U2*)(ring + 7*128  + 2*tt); \
    U2 q8  = *(const U2*)(ring + 8*128  + 2*tt); \
    U2 q9  = *(const U2*)(ring + 9*128  + 2*tt); \
    U2 q10 = *(const U2*)(ring + 10*128 + 2*tt); \
    U2 q11 = *(const U2*)(ring + 11*128 + 2*tt); \
    u64 o0 = 0, o1 = 0; \
    o0 |= (m0 && nf > 0)  ? q0.x  : 0ULL;  o1 |= (m1 && nf > 0)  ? q0.y  : 0ULL; \
    o0 |= (m0 && nf > 1)  ? q1.x  : 0ULL;  o1 |= (m1 && nf > 1)  ? q1.y  : 0ULL; \
    o0 |= (m0 && nf > 2)  ? q2.x  : 0ULL;  o1 |= (m1 && nf > 2)  ? q2.y  : 0ULL; \
    o0 |= (m0 && nf > 3)  ? q3.x  : 0ULL;  o1 |= (m1 && nf > 3)  ? q3.y  : 0ULL; \
    o0 |= (m0 && nf > 4)  ? q4.x  : 0ULL;  o1 |= (m1 && nf > 4)  ? q4.y  : 0ULL; \
    o0 |= (m0 && nf > 5)  ? q5.x  : 0ULL;  o1 |= (m1 && nf > 5)  ? q5.y  : 0ULL; \
    o0 |= (m0 && nf > 6)  ? q6.x  : 0ULL;  o1 |= (m1 && nf > 6)  ? q6.y  : 0ULL; \
    o0 |= (m0 && nf > 7)  ? q7.x  : 0ULL;  o1 |= (m1 && nf > 7)  ? q7.y  : 0ULL; \
    o0 |= (m0 && nf > 8)  ? q8.x  : 0ULL;  o1 |= (m1 && nf > 8)  ? q8.y  : 0ULL; \
    o0 |= (m0 && nf > 9)  ? q9.x  : 0ULL;  o1 |= (m1 && nf > 9)  ? q9.y  : 0ULL; \
    o0 |= (m0 && nf > 10) ? q10.x : 0ULL;  o1 |= (m1 && nf > 10) ? q10.y : 0ULL; \
    o0 |= (m0 && nf > 11) ? q11.x : 0ULL;  o1 |= (m1 && nf > 11) ? q11.y : 0ULL; \
    rv0 |= o0; rv1 |= o1; \
  } while (0)

  for (int b = 0; b < NBLK; ++b) {
    u64 cc = (b & 1) ? colB : colA;
    // deferred flush of previous block's kept rows (stages issued ~a block ago — latency mostly hidden)
    if (pslot > 0) { FLUSHRING(pslot, pblk); pslot = 0; }
    int base = b * 64;
    // carry-in from all previously-kept rows (word b lives on lane b>>1, slot b&1)
    u64 w = rl64((b & 1) ? rv1 : rv0, b >> 1);
    int nv = N - base; if (nv > 64) nv = 64;
    u64 valid = (nv >= 64) ? ~0ULL : ((1ULL << nv) - 1ULL);
    u64 avail = ~w & valid;
    // prefetch next block's diagonal column — single coalesced 512B transaction
    if (b + 1 < NBLK) {
      u64 nx = diag[(b + 1) * 64 + t];
      if (b & 1) colA = nx; else colB = nx;
    }
    int slot = 0;
    // predicated 4x-unrolled scan: every sub-iteration is branch-free ALU + one stage issue
    while (avail && kept < TOPN) {
#pragma unroll
      for (int u = 0; u < 4; ++u) {
        bool on = (avail != 0ULL) && (kept < TOPN);
        int d = (int)__builtin_ctzll(avail | (1ULL << 63));  // d in [0,63]
        int row = base + d;
        klist[on ? kept : TOPN] = row;                       // all lanes, same addr+value
        // stage full mask row into ring (off-iterations -> dump slot 12; no same-slot races)
        gload_lds16((const char*)(mask + (size_t)row * NW) + (size_t)tt * 16,
                    (void*)(ring + (size_t)(on ? slot : 12) * 128));
        u64 sup = rl64(cc, d);
        u64 clear = on ? (sup | (1ULL << d)) : 0ULL;
        avail &= ~clear;
        kept += on ? 1 : 0;
        slot += on ? 1 : 0;
      }
      if (slot >= 8) { FLUSHRING(slot, b); slot = 0; }       // slot <= 11; rare (block keeps >=8)
    }
    if (kept >= TOPN) break;                                 // remaining drain is dead work
    pslot = slot;
    pblk = b;
  }
  __syncthreads();
  // epilogue: write the FULL 300x5 output (zeros where unfilled)
  for (int e = t; e < TOPN * 5; e += 64) {
    int row = e / 5, col = e % 5;
    float v = 0.0f;
    if (col > 0 && row < kept) v = sboxes[klist[row] * 4 + (col - 1)];
    out[e] = v;
  }
#undef FLUSHRING
}

extern "C" void kernel_launch(void* const* d_in, const int* in_sizes, int n_in,
                              void* d_out, int out_size, void* d_ws, size_t ws_size,
                              hipStream_t stream) {
  const float* cls  = (const float*)d_in[0];
  const float* pred = (const float*)d_in[1];
  const int*   imi  = (const int*)d_in[2];
  const float* mean = (const float*)d_in[3];
  const float* stdv = (const float*)d_in[4];
  float* out = (float*)d_out;

  char* ws = (char*)d_ws;
  float* boxes  = (float*)(ws);                        // NB*4 floats   = 277440 B
  u32*   sbits  = (u32*)(ws + 277440);                 // NB u32        = 69360 B
  float* sboxes = (float*)(ws + 346800);               // MAXC*4 floats = 80000 B
  int*   cnt    = (int*)(ws + 426800);                 // 16 B
  int*   hist   = (int*)(ws + 426816);                 // NBUCK ints    = 20480 B
  int*   fill   = (int*)(ws + 447296);                 // NBUCK ints    = 20480 B
  int*   base   = (int*)(ws + 467776);                 // NBUCK ints    = 20480 B
  u64*   mask   = (u64*)(ws + 488256);                 // NRALLOC*NW*8  = 3235840 B
  u64*   blist  = mask;   // alias: blist (<=138720 B) dead before k_iou writes mask
  u64*   diag   = (u64*)(ws + 426816);  // 40448 B; overlaps hist+fill (both dead after k_place)

  hipMemsetAsync(hist, 0, 2 * NBUCK * sizeof(int), stream);   // hist + fill (contiguous)

  k_decode<<<(NB + 255) / 256, 256, 0, stream>>>(cls, pred, imi, mean, stdv, boxes, sbits, hist);
  k_scan<<<1, 1024, 0, stream>>>(hist, base, cnt);
  k_place<<<(NB + 255) / 256, 256, 0, stream>>>(sbits, base, fill, blist);
  k_final<<<(NB + 255) / 256, 256, 0, stream>>>(sbits, base, cnt, blist, boxes, sboxes);
  dim3 giou((MAXC + 63) / 64, NW);
  k_iou<<<giou, 64, 0, stream>>>(sboxes, cnt, mask, diag);
  k_nms<<<1, 64, 0, stream>>>(sboxes, mask, diag, cnt, out);
}

// Round 25
// 93.322 us; speedup vs baseline: 3.6942x; 1.0161x over previous
//
#include <hip/hip_runtime.h>

#define NA 15
#define GH 34
#define GW 34
#define SP (GH*GW)          // 1156
#define NB (SP*NA)          // 17340
#define MAXC 5000
#define TOPN 300
#define NW 80               // padded words per mask row (79 used + 1 pad)
#define NRALLOC 5056        // mask rows allocated
#define THRESH_OBJ 0.2f
#define NMS_T 0.7f
// score-bucket constants: positive-float bits are order-preserving
#define SH 12
#define BLO 0x3E4CCu        // bits(0.2f) >> 12
#define NBUCK 5120          // covers bits(1.0)>>12 - BLO = 4916, 5 per scan-thread

typedef unsigned long long u64;
typedef unsigned int u32;
struct __align__(16) U2 { u64 x, y; };

__constant__ float c_aw[NA] = {45.3f,32.0f,22.6f,90.5f,64.0f,45.3f,181.0f,128.0f,90.5f,271.5f,192.0f,135.8f,362.0f,256.0f,181.0f};
__constant__ float c_ah[NA] = {22.6f,32.0f,45.3f,45.3f,64.0f,90.5f,90.5f,128.0f,181.0f,135.8f,192.0f,271.5f,181.0f,256.0f,362.0f};

// ---------------- decode: anchors + deltas -> proposals + score bits + global histogram ----------------
__global__ __launch_bounds__(256) void k_decode(
    const float* __restrict__ cls, const float* __restrict__ pred,
    const int* __restrict__ iminfo, const float* __restrict__ mean,
    const float* __restrict__ stdv, float* __restrict__ boxes,
    u32* __restrict__ sbits, int* __restrict__ hist) {
#pragma clang fp contract(off)
  int r = blockIdx.x * 256 + threadIdx.x;
  if (r >= NB) return;
  int n = r % NA;
  int p = r / NA;       // p = h*GW + w
  int w = p % GW;
  int h = p / GW;

  float score = cls[(NA + n) * SP + p];             // channel NA+n, spatial p

  float d0 = pred[(n*4+0)*SP + p] * stdv[0] + mean[0];
  float d1 = pred[(n*4+1)*SP + p] * stdv[1] + mean[1];
  float d2 = pred[(n*4+2)*SP + p] * stdv[2] + mean[2];
  float d3 = pred[(n*4+3)*SP + p] * stdv[3] + mean[3];

  float aw = c_aw[n], ah = c_ah[n];
  float sx = (float)(w * 16);
  float sy = (float)(h * 16);
  float xmin = -0.5f * (aw - 1.0f) + sx;
  float ymin = -0.5f * (ah - 1.0f) + sy;
  float xmax =  0.5f * (aw - 1.0f) + sx;
  float ymax =  0.5f * (ah - 1.0f) + sy;

  float widths  = xmax - xmin + 1.0f;
  float heights = ymax - ymin + 1.0f;
  float ctrx = xmin + 0.5f * (widths - 1.0f);
  float ctry = ymin + 0.5f * (heights - 1.0f);

  float pcx = d0 * widths + ctrx;
  float pcy = d1 * heights + ctry;
  float pw = expf(d2) * widths;
  float ph = expf(d3) * heights;

  float x1 = pcx - 0.5f * (pw - 1.0f);
  float y1 = pcy - 0.5f * (ph - 1.0f);
  float x2 = pcx + 0.5f * (pw - 1.0f);
  float y2 = pcy + 0.5f * (ph - 1.0f);

  float ow = (float)iminfo[1] - 1.0f;
  float oh = (float)iminfo[0] - 1.0f;
  x1 = fminf(fmaxf(x1, 0.0f), ow);
  x2 = fminf(fmaxf(x2, 0.0f), ow);
  y1 = fminf(fmaxf(y1, 0.0f), oh);
  y2 = fminf(fmaxf(y2, 0.0f), oh);

  float ws = x2 - x1 + 1.0f;
  float hs = y2 - y1 + 1.0f;
  bool keep = (score > THRESH_OBJ) && (ws >= 6.0f) && (hs >= 6.0f);

  boxes[r*4+0] = x1;
  boxes[r*4+1] = y1;
  boxes[r*4+2] = x2;
  boxes[r*4+3] = y2;
  u32 bits = keep ? __float_as_uint(score) : 0u;
  sbits[r] = bits;
  if (bits) {
    int b = min((int)((bits >> SH) - BLO), NBUCK - 1);
    atomicAdd(&hist[b], 1);
  }
}

// ------- suffix-scan of bucket histogram (wave-level, 1 barrier): base[b] = #elems in buckets > b -------
__global__ __launch_bounds__(1024) void k_scan(const int* __restrict__ hist,
    int* __restrict__ base, int* __restrict__ cnt) {
  __shared__ int sh[NBUCK];
  __shared__ int wt[16];
  int tid = threadIdx.x;
  for (int j = tid; j < NBUCK; j += 1024) sh[j] = hist[j];
  __syncthreads();
  int c0 = sh[tid*5+0], c1 = sh[tid*5+1], c2 = sh[tid*5+2], c3 = sh[tid*5+3], c4 = sh[tid*5+4];
  int c = c0 + c1 + c2 + c3 + c4;
  int lane = tid & 63;
  // inclusive suffix scan within wave (shfl_down, barrier-free)
  int P = c;
  for (int off = 1; off < 64; off <<= 1) {
    int v = __shfl_down(P, off, 64);
    P += (lane + off < 64) ? v : 0;
  }
  if (lane == 0) wt[tid >> 6] = P;      // wave total = inclusive suffix at lane 0
  __syncthreads();
  int later = 0;
#pragma unroll
  for (int wvi = 0; wvi < 16; ++wvi) later += (wvi > (tid >> 6)) ? wt[wvi] : 0;
  int S = P - c + later;                // exclusive suffix over chunks after tid
  int b4 = S;
  int b3 = b4 + c4;
  int b2 = b3 + c3;
  int b1 = b2 + c2;
  int b0 = b1 + c1;
  base[tid*5+0] = b0; base[tid*5+1] = b1; base[tid*5+2] = b2;
  base[tid*5+3] = b3; base[tid*5+4] = b4;
  if (tid == 0) *cnt = P + later;       // total active
}

// ---------------- place keys into bucket slots (order within bucket irrelevant) ----------------
__global__ __launch_bounds__(256) void k_place(const u32* __restrict__ sbits,
    const int* __restrict__ base, int* __restrict__ fill, u64* __restrict__ blist) {
  int i = blockIdx.x * 256 + threadIdx.x;
  if (i >= NB) return;
  u32 bits = sbits[i];
  if (!bits) return;
  int b = min((int)((bits >> SH) - BLO), NBUCK - 1);
  int pos = base[b] + atomicAdd(&fill[b], 1);
  blist[pos] = ((u64)bits << 32) | (u64)(0xFFFFFFFFu - (u32)i);
}

// ---------------- exact rank = base[b] + within-bucket greater-count; scatter ----------------
__global__ __launch_bounds__(256) void k_final(const u32* __restrict__ sbits,
    const int* __restrict__ base, const int* __restrict__ cnt,
    const u64* __restrict__ blist, const float* __restrict__ boxes,
    float* __restrict__ sboxes) {
  int i = blockIdx.x * 256 + threadIdx.x;
  if (i >= NB) return;
  u32 bits = sbits[i];
  if (!bits) return;
  int b = min((int)((bits >> SH) - BLO), NBUCK - 1);
  u64 key = ((u64)bits << 32) | (u64)(0xFFFFFFFFu - (u32)i);
  int s = base[b];
  int e = (b > 0) ? base[b-1] : *cnt;
  int r = s;
  for (int p = s; p < e; ++p) r += (blist[p] > key) ? 1 : 0;
  if (r < MAXC) ((float4*)sboxes)[r] = ((const float4*)boxes)[i];
}

// --- pairwise IoU bitmask, UPPER-TRI ONLY (no zero-fill); diagonal blocks write diag[] ---
__global__ __launch_bounds__(64) void k_iou(const float* __restrict__ sboxes,
    const int* __restrict__ cnt, u64* __restrict__ mask, u64* __restrict__ diag) {
#pragma clang fp contract(off)
  int N = min(*cnt, MAXC);
  int bi = blockIdx.x, bj = blockIdx.y;
  if (bj < bi) return;                // k_nms masks unwritten lower-tri words by block index
  int t = threadIdx.x;
  int i = bi * 64 + t;
  if (bi * 64 >= N) return;
  __shared__ float4 jb[64];
  int j0 = bj * 64;
  if (j0 + t < N) jb[t] = ((const float4*)sboxes)[j0 + t];
  __syncthreads();
  if (i >= N) return;
  float4 a = ((const float4*)sboxes)[i];
  float areaA = (a.z - a.x + 1.0f) * (a.w - a.y + 1.0f);
  u64 word = 0;
  int jmax = min(64, N - j0);         // <=0 for pad word 79 -> writes 0
  for (int jj = 0; jj < jmax; ++jj) {
    int j = j0 + jj;
    if (j <= i) continue;
    float4 b = jb[jj];
    float iw = fminf(a.z, b.z) - fmaxf(a.x, b.x) + 1.0f;
    float ih = fminf(a.w, b.w) - fmaxf(a.y, b.y) + 1.0f;
    iw = fmaxf(iw, 0.0f);
    ih = fmaxf(ih, 0.0f);
    float inter = iw * ih;
    float areaB = (b.z - b.x + 1.0f) * (b.w - b.y + 1.0f);
    float iou = inter / (areaA + areaB - inter);
    if (iou > NMS_T) word |= (1ULL << jj);
  }
  mask[(size_t)i * NW + bj] = word;
  if (bi == bj) diag[i] = word;       // compact diagonal: coalesced column read in k_nms
}

// ---- serial greedy NMS: diag column + predicated scan + issue-on-keep staging;
// ---- flush masks lower-tri junk with a WAVE-UNIFORM block-index compare (no per-row data) ----
__device__ __forceinline__ u64 rl64(u64 v, int l) {
  unsigned lo = __builtin_amdgcn_readlane((unsigned)(v & 0xffffffffULL), l);
  unsigned hi = __builtin_amdgcn_readlane((unsigned)(v >> 32), l);
  return ((u64)hi << 32) | (u64)lo;
}

__device__ __forceinline__ void gload_lds16(const void* g, void* l) {
  __builtin_amdgcn_global_load_lds(
      (const __attribute__((address_space(1))) unsigned int*)g,
      (__attribute__((address_space(3))) unsigned int*)l, 16, 0, 0);
}

__global__ __launch_bounds__(64, 1) void k_nms(const float* __restrict__ sboxes,
    const u64* __restrict__ mask, const u64* __restrict__ diag,
    const int* __restrict__ cnt, float* __restrict__ out) {
  const int t = threadIdx.x;
  const int N = min(*cnt, MAXC);
  const int NBLK = (N + 63) >> 6;          // <= 79
  const int tt = (t < 40) ? t : 39;        // lane covers row bytes [16tt,16tt+16) = words 2tt,2tt+1
  const bool lane_ok = (t < 40);
  const int w0i = 2 * tt, w1i = 2 * tt + 1;
  u64 rv0 = 0ULL, rv1 = 0ULL;              // remv: lane t owns words 2t, 2t+1 (t<40)
  __shared__ int klist[TOPN + 1];          // slot TOPN = dump for predicated-off stores
  __shared__ __align__(16) u64 ring[13 * 128];  // 12 slots + dump slot 12 (1KB each)
  int kept = 0;

  u64 colA = 0ULL, colB = 0ULL;            // ping-pong diagonal columns — coalesced loads
  if (NBLK > 0) colA = diag[t];
  int pslot = 0;                           // pending ring entries from previous block
  int pblk = 0;                            // block index of pending rows

  // flush nf pending ring slots (rows all from block bq_) into rv0/rv1.
  // words < bq are unwritten junk -> masked by wave-uniform compare (m0/m1).
#define FLUSHRING(n_, bq_) do { \
    asm volatile("s_waitcnt vmcnt(0)" ::: "memory"); \
    __builtin_amdgcn_sched_barrier(0); \
    int nf = (n_); int bq = (bq_); \
    bool m0 = lane_ok && (w0i >= bq); \
    bool m1 = lane_ok && (w1i >= bq); \
    U2 q0  = *(const U2*)(ring + 0*128  + 2*tt); \
    U2 q1  = *(const U2*)(ring + 1*128  + 2*tt); \
    U2 q2  = *(const U2*)(ring + 2*128  + 2*tt); \
    U2 q3  = *(const U2*)(ring + 3*128  + 2*tt); \
    U2 q4  = *(const U2*)(ring + 4*128  + 2*tt); \
    U2 q5  = *(const U2*)(ring + 5*128  + 2*tt); \
    U2 q6  = *(const U2*)(ring + 6*128  + 2*tt); \
    U2 q7  = *(const U2*)(ring + 7*128  + 2*tt); \
    U2 q8  = *(const U2*)(ring + 8*128  + 2*tt); \
    U2 q9  = *(const U2*)(ring + 9*128  + 2*tt); \
    U2 q10 = *(const U2*)(ring + 10*128 + 2*tt); \
    U2 q11 = *(const U2*)(ring + 11*128 + 2*tt); \
    u64 o0 = 0, o1 = 0; \
    o0 |= (m0 && nf > 0)  ? q0.x  : 0ULL;  o1 |= (m1 && nf > 0)  ? q0.y  : 0ULL; \
    o0 |= (m0 && nf > 1)  ? q1.x  : 0ULL;  o1 |= (m1 && nf > 1)  ? q1.y  : 0ULL; \
    o0 |= (m0 && nf > 2)  ? q2.x  : 0ULL;  o1 |= (m1 && nf > 2)  ? q2.y  : 0ULL; \
    o0 |= (m0 && nf > 3)  ? q3.x  : 0ULL;  o1 |= (m1 && nf > 3)  ? q3.y  : 0ULL; \
    o0 |= (m0 && nf > 4)  ? q4.x  : 0ULL;  o1 |= (m1 && nf > 4)  ? q4.y  : 0ULL; \
    o0 |= (m0 && nf > 5)  ? q5.x  : 0ULL;  o1 |= (m1 && nf > 5)  ? q5.y  : 0ULL; \
    o0 |= (m0 && nf > 6)  ? q6.x  : 0ULL;  o1 |= (m1 && nf > 6)  ? q6.y  : 0ULL; \
    o0 |= (m0 && nf > 7)  ? q7.x  : 0ULL;  o1 |= (m1 && nf > 7)  ? q7.y  : 0ULL; \
    o0 |= (m0 && nf > 8)  ? q8.x  : 0ULL;  o1 |= (m1 && nf > 8)  ? q8.y  : 0ULL; \
    o0 |= (m0 && nf > 9)  ? q9.x  : 0ULL;  o1 |= (m1 && nf > 9)  ? q9.y  : 0ULL; \
    o0 |= (m0 && nf > 10) ? q10.x : 0ULL;  o1 |= (m1 && nf > 10) ? q10.y : 0ULL; \
    o0 |= (m0 && nf > 11) ? q11.x : 0ULL;  o1 |= (m1 && nf > 11) ? q11.y : 0ULL; \
    rv0 |= o0; rv1 |= o1; \
  } while (0)

  for (int b = 0; b < NBLK; ++b) {
    u64 cc = (b & 1) ? colB : colA;
    // deferred flush of previous block's kept rows (stages issued ~a block ago — latency mostly hidden)
    if (pslot > 0) { FLUSHRING(pslot, pblk); pslot = 0; }
    int base = b * 64;
    // carry-in from all previously-kept rows (word b lives on lane b>>1, slot b&1)
    u64 w = rl64((b & 1) ? rv1 : rv0, b >> 1);
    int nv = N - base; if (nv > 64) nv = 64;
    u64 valid = (nv >= 64) ? ~0ULL : ((1ULL << nv) - 1ULL);
    u64 avail = ~w & valid;
    // prefetch next block's diagonal column — single coalesced 512B transaction
    if (b + 1 < NBLK) {
      u64 nx = diag[(b + 1) * 64 + t];
      if (b & 1) colA = nx; else colB = nx;
    }
    int slot = 0;
    // predicated 4x-unrolled scan: every sub-iteration is branch-free ALU + one stage issue
    while (avail && kept < TOPN) {
#pragma unroll
      for (int u = 0; u < 4; ++u) {
        bool on = (avail != 0ULL) && (kept < TOPN);
        int d = (int)__builtin_ctzll(avail | (1ULL << 63));  // d in [0,63]
        int row = base + d;
        klist[on ? kept : TOPN] = row;                       // all lanes, same addr+value
        // stage full mask row into ring (off-iterations -> dump slot 12; no same-slot races)
        gload_lds16((const char*)(mask + (size_t)row * NW) + (size_t)tt * 16,
                    (void*)(ring + (size_t)(on ? slot : 12) * 128));
        u64 sup = rl64(cc, d);
        u64 clear = on ? (sup | (1ULL << d)) : 0ULL;
        avail &= ~clear;
        kept += on ? 1 : 0;
        slot += on ? 1 : 0;
      }
      if (slot >= 8) { FLUSHRING(slot, b); slot = 0; }       // slot <= 11; rare (block keeps >=8)
    }
    if (kept >= TOPN) break;                                 // remaining drain is dead work
    pslot = slot;
    pblk = b;
  }
  __syncthreads();
  // epilogue: write the FULL 300x5 output (zeros where unfilled)
  for (int e = t; e < TOPN * 5; e += 64) {
    int row = e / 5, col = e % 5;
    float v = 0.0f;
    if (col > 0 && row < kept) v = sboxes[klist[row] * 4 + (col - 1)];
    out[e] = v;
  }
#undef FLUSHRING
}

extern "C" void kernel_launch(void* const* d_in, const int* in_sizes, int n_in,
                              void* d_out, int out_size, void* d_ws, size_t ws_size,
                              hipStream_t stream) {
  const float* cls  = (const float*)d_in[0];
  const float* pred = (const float*)d_in[1];
  const int*   imi  = (const int*)d_in[2];
  const float* mean = (const float*)d_in[3];
  const float* stdv = (const float*)d_in[4];
  float* out = (float*)d_out;

  char* ws = (char*)d_ws;
  float* boxes  = (float*)(ws);                        // NB*4 floats   = 277440 B
  u32*   sbits  = (u32*)(ws + 277440);                 // NB u32        = 69360 B
  float* sboxes = (float*)(ws + 346800);               // MAXC*4 floats = 80000 B
  int*   cnt    = (int*)(ws + 426800);                 // 16 B
  int*   hist   = (int*)(ws + 426816);                 // NBUCK ints    = 20480 B
  int*   fill   = (int*)(ws + 447296);                 // NBUCK ints    = 20480 B
  int*   base   = (int*)(ws + 467776);                 // NBUCK ints    = 20480 B
  u64*   mask   = (u64*)(ws + 488256);                 // NRALLOC*NW*8  = 3235840 B
  u64*   blist  = mask;   // alias: blist (<=138720 B) dead before k_iou writes mask
  u64*   diag   = (u64*)(ws + 426816);  // 40448 B; overlaps hist+fill (both dead after k_place)

  hipMemsetAsync(hist, 0, 2 * NBUCK * sizeof(int), stream);   // hist + fill (contiguous)

  k_decode<<<(NB + 255) / 256, 256, 0, stream>>>(cls, pred, imi, mean, stdv, boxes, sbits, hist);
  k_scan<<<1, 1024, 0, stream>>>(hist, base, cnt);
  k_place<<<(NB + 255) / 256, 256, 0, stream>>>(sbits, base, fill, blist);
  k_final<<<(NB + 255) / 256, 256, 0, stream>>>(sbits, base, cnt, blist, boxes, sboxes);
  dim3 giou((MAXC + 63) / 64, NW);
  k_iou<<<giou, 64, 0, stream>>>(sboxes, cnt, mask, diag);
  k_nms<<<1, 64, 0, stream>>>(sboxes, mask, diag, cnt, out);
}